// Round 7
// baseline (4836.122 us; speedup 1.0000x reference)
//
#include <hip/hip_runtime.h>
#include <cstdint>
#include <cstddef>

typedef unsigned int u32;
typedef unsigned long long u64;
typedef __attribute__((ext_vector_type(8))) short s8v;   // 8 bf16 (4 VGPRs)
typedef __attribute__((ext_vector_type(4))) float f4v;   // MFMA C/D

#define B_   2
#define L_   2048
#define D_   1024
#define NH_  16
#define KVH_ 8
#define DH_  64
#define TOPK_ 1024

#define MFMA16(a, b, c) __builtin_amdgcn_mfma_f32_16x16x32_bf16(a, b, c, 0, 0, 0)

// order-preserving float->uint key (descending float == descending uint)
__device__ __forceinline__ u32 fkey(float s) {
    u32 b = __float_as_uint(s);
    return b ^ ((u32)((int)b >> 31) | 0x80000000u);
}
// exact inverse of fkey
__device__ __forceinline__ float fkeyinv(u32 k) {
    u32 b = (k & 0x80000000u) ? (k ^ 0x80000000u) : ~k;
    return __uint_as_float(b);
}
// fp32 -> bf16 round-to-nearest-even, as raw ushort
__device__ __forceinline__ unsigned short bf16rne(float x) {
    u32 u = __float_as_uint(x);
    u32 r = (u + 0x7FFFu + ((u >> 16) & 1u)) >> 16;
    return (unsigned short)r;
}
__device__ __forceinline__ float bf2f(unsigned short h) {
    return __uint_as_float((u32)h << 16);
}

// ---------------------------------------------------------------------------
// W [K][N] fp32 -> WtH/WtL [N][K] bf16 hi/lo (transpose + split). grid (K/64, N/64)
// ---------------------------------------------------------------------------
__global__ __launch_bounds__(256) void prep_wt(const float* __restrict__ W,
                                               unsigned short* __restrict__ WtH,
                                               unsigned short* __restrict__ WtL,
                                               int K, int N) {
    __shared__ float tile[64 * 65];
    int k0 = blockIdx.x * 64, n0 = blockIdx.y * 64;
    int t = threadIdx.x;
#pragma unroll
    for (int i = 0; i < 16; ++i) {
        int idx = t + i * 256;
        int kk = idx >> 6, nn = idx & 63;
        tile[kk * 65 + nn] = W[(size_t)(k0 + kk) * N + n0 + nn];
    }
    __syncthreads();
#pragma unroll
    for (int i = 0; i < 16; ++i) {
        int idx = t + i * 256;
        int nn = idx >> 6, kk = idx & 63;
        float x = tile[kk * 65 + nn];
        unsigned short hi = bf16rne(x);
        unsigned short lo = bf16rne(x - bf2f(hi));
        WtH[(size_t)(n0 + nn) * K + k0 + kk] = hi;
        WtL[(size_t)(n0 + nn) * K + k0 + kk] = lo;
    }
}

// ---------------------------------------------------------------------------
// MFMA GEMM: C[M][N] fp32 = A[M][K] fp32 @ Wt([N][K] bf16 hi/lo), 3-term hi/lo.
// BM=128, BN=128, BK=32; 256 threads (4 waves, 2x2 of 64x64). grid (M/128, N/128)
// ---------------------------------------------------------------------------
__global__ __launch_bounds__(256) void gemm_mfma(
    const float* __restrict__ A,
    const unsigned short* __restrict__ Wh,
    const unsigned short* __restrict__ Wl,
    float* __restrict__ C, int K, int N) {
    __shared__ __align__(16) unsigned short lAh[128 * 40];
    __shared__ __align__(16) unsigned short lAl[128 * 40];
    __shared__ __align__(16) unsigned short lBh[128 * 40];
    __shared__ __align__(16) unsigned short lBl[128 * 40];
    const int t = threadIdx.x, lane = t & 63, w = t >> 6;
    const int quad = lane >> 4, col = lane & 15;
    const int wm = w >> 1, wn = w & 1;
    const int m0 = blockIdx.x * 128, n0 = blockIdx.y * 128;
    const int sr = t >> 1, sk = (t & 1) * 16;

    f4v acc[4][4];
#pragma unroll
    for (int i = 0; i < 4; ++i)
#pragma unroll
        for (int j = 0; j < 4; ++j) acc[i][j] = (f4v){0.f, 0.f, 0.f, 0.f};

    for (int k0 = 0; k0 < K; k0 += 32) {
        const float* ap = A + (size_t)(m0 + sr) * K + k0 + sk;
        float4 a0 = *(const float4*)(ap);
        float4 a1 = *(const float4*)(ap + 4);
        float4 a2 = *(const float4*)(ap + 8);
        float4 a3 = *(const float4*)(ap + 12);
        s8v bh0 = *(const s8v*)(Wh + (size_t)(n0 + sr) * K + k0 + sk);
        s8v bh1 = *(const s8v*)(Wh + (size_t)(n0 + sr) * K + k0 + sk + 8);
        s8v bl0 = *(const s8v*)(Wl + (size_t)(n0 + sr) * K + k0 + sk);
        s8v bl1 = *(const s8v*)(Wl + (size_t)(n0 + sr) * K + k0 + sk + 8);
        float av[16] = {a0.x, a0.y, a0.z, a0.w, a1.x, a1.y, a1.z, a1.w,
                        a2.x, a2.y, a2.z, a2.w, a3.x, a3.y, a3.z, a3.w};
        union { s8v v; unsigned short u[8]; } ah_[2], al_[2];
#pragma unroll
        for (int i = 0; i < 16; ++i) {
            unsigned short hi = bf16rne(av[i]);
            ah_[i >> 3].u[i & 7] = hi;
            al_[i >> 3].u[i & 7] = bf16rne(av[i] - bf2f(hi));
        }
        __syncthreads();
        *(s8v*)&lAh[sr * 40 + sk]     = ah_[0].v;
        *(s8v*)&lAh[sr * 40 + sk + 8] = ah_[1].v;
        *(s8v*)&lAl[sr * 40 + sk]     = al_[0].v;
        *(s8v*)&lAl[sr * 40 + sk + 8] = al_[1].v;
        *(s8v*)&lBh[sr * 40 + sk]     = bh0;
        *(s8v*)&lBh[sr * 40 + sk + 8] = bh1;
        *(s8v*)&lBl[sr * 40 + sk]     = bl0;
        *(s8v*)&lBl[sr * 40 + sk + 8] = bl1;
        __syncthreads();
        s8v amh[4], aml[4], bnh[4], bnl[4];
#pragma unroll
        for (int mt = 0; mt < 4; ++mt) {
            amh[mt] = *(s8v*)&lAh[(wm * 64 + mt * 16 + col) * 40 + quad * 8];
            aml[mt] = *(s8v*)&lAl[(wm * 64 + mt * 16 + col) * 40 + quad * 8];
        }
#pragma unroll
        for (int nt = 0; nt < 4; ++nt) {
            bnh[nt] = *(s8v*)&lBh[(wn * 64 + nt * 16 + col) * 40 + quad * 8];
            bnl[nt] = *(s8v*)&lBl[(wn * 64 + nt * 16 + col) * 40 + quad * 8];
        }
#pragma unroll
        for (int mt = 0; mt < 4; ++mt)
#pragma unroll
            for (int nt = 0; nt < 4; ++nt) {
                acc[mt][nt] = MFMA16(amh[mt], bnh[nt], acc[mt][nt]);
                acc[mt][nt] = MFMA16(amh[mt], bnl[nt], acc[mt][nt]);
                acc[mt][nt] = MFMA16(aml[mt], bnh[nt], acc[mt][nt]);
            }
    }
#pragma unroll
    for (int mt = 0; mt < 4; ++mt)
#pragma unroll
        for (int nt = 0; nt < 4; ++nt)
#pragma unroll
            for (int r = 0; r < 4; ++r)
                C[(size_t)(m0 + wm * 64 + mt * 16 + quad * 4 + r) * N +
                  n0 + wn * 64 + nt * 16 + col] = acc[mt][nt][r];
}

// ---------------------------------------------------------------------------
// RoPE on Q, in place. Layout [b][l][h][d].
// ---------------------------------------------------------------------------
__global__ __launch_bounds__(256) void rope_q(float* __restrict__ Q,
                                              const int* __restrict__ pos) {
    int tid = blockIdx.x * 256 + threadIdx.x;
    int dl = tid & 31;
    int h  = (tid >> 5) & 15;
    int l  = (tid >> 9) & 2047;
    int b  = tid >> 20;
    size_t base = ((size_t)(b * L_ + l) * NH_ + h) * DH_;
    float x1 = Q[base + dl];
    float x2 = Q[base + dl + 32];
    float p = (float)pos[b * L_ + l];
    float invf = (float)pow(10000.0, -(double)dl / 32.0);
    float a = p * invf;
    float s, c;
    sincosf(a, &s, &c);
    Q[base + dl]      = x1 * c - x2 * s;
    Q[base + dl + 32] = x2 * c + x1 * s;
}

// ---------------------------------------------------------------------------
// RoPE on K + hi/lo bf16 split, layout [b][kvh][l][d]
// ---------------------------------------------------------------------------
__global__ __launch_bounds__(256) void prep_k(const float* __restrict__ Kraw,
                                              unsigned short* __restrict__ KHp,
                                              unsigned short* __restrict__ KLp,
                                              const int* __restrict__ pos) {
    int tid = blockIdx.x * 256 + threadIdx.x;
    int d   = tid & 63;
    int l   = (tid >> 6) & 2047;
    int kvh = (tid >> 17) & 7;
    int b   = tid >> 20;
    size_t src = ((size_t)(b * L_ + l) * KVH_ + kvh) * DH_;
    float x  = Kraw[src + d];
    int dp   = (d < 32) ? d + 32 : d - 32;
    float xp = Kraw[src + dp];
    float p = (float)pos[b * L_ + l];
    int i = d & 31;
    float invf = (float)pow(10000.0, -(double)i / 32.0);
    float a = p * invf;
    float s, c;
    sincosf(a, &s, &c);
    float out = (d < 32) ? (x * c - xp * s) : (x * c + xp * s);
    unsigned short hi = bf16rne(out);
    unsigned short lo = bf16rne(out - bf2f(hi));
    size_t dst = ((size_t)(b * KVH_ + kvh) * L_ + l) * DH_ + d;
    KHp[dst] = hi;
    KLp[dst] = lo;
}

// ---------------------------------------------------------------------------
// V transpose to bf16: Vraw[b][l][kvh][d] -> VT[b][kvh][d][l]
// ---------------------------------------------------------------------------
__global__ __launch_bounds__(256) void prep_v(const float* __restrict__ Vraw,
                                              unsigned short* __restrict__ VTp) {
    __shared__ float tile[64 * 65];
    int bid = blockIdx.x;
    int lb  = bid & 31;
    int kvh = (bid >> 5) & 7;
    int b   = bid >> 8;
    int l0  = lb * 64;
    int t   = threadIdx.x;
#pragma unroll
    for (int i = 0; i < 16; ++i) {
        int idx = t + i * 256;
        int ll = idx >> 6, d = idx & 63;
        tile[ll * 65 + d] = Vraw[((size_t)(b * L_ + l0 + ll) * KVH_ + kvh) * DH_ + d];
    }
    __syncthreads();
#pragma unroll
    for (int i = 0; i < 16; ++i) {
        int idx = t + i * 256;
        int d = idx >> 6, ll = idx & 63;
        VTp[((size_t)(b * KVH_ + kvh) * DH_ + d) * L_ + l0 + ll] = bf16rne(tile[ll * 65 + d]);
    }
}

// ---------------------------------------------------------------------------
// Fused sparse attention, 16 q-rows/block, 1024 threads (16 waves), grid 4096.
// R7 changes vs R6 (LDS-pipe + barrier surgery; algorithm identical):
//  - pass-0 radix histogram via match-any ballots: one atomicAdd(popcount) per
//    distinct digit per iteration (scores concentrate in ~6 top-byte bins ->
//    R6's per-lane atomics serialized same-address across the wave).
//  - transposed hist layout (d&3)*64+(d>>2): conflict-free zero/read.
//  - padded strides: Sc row 1044 f32, Pc row 2072 b16, outred row 68.
//  - transpose 2 chunks (was 4), PV 1 chunk (was 2), hist unioned: 8 barriers.
// ---------------------------------------------------------------------------
__global__ __launch_bounds__(1024) void attn(
    const float* __restrict__ QR,
    const unsigned short* __restrict__ KH,
    const unsigned short* __restrict__ KL,
    const unsigned short* __restrict__ VT,
    float* __restrict__ AO) {

    __shared__ __align__(16) union {
        float Sc[16 * 1044];             // transpose: 2 chunks of 1024 cols
        unsigned short Pc[16 * 2072];    // P full rows (bf16)
        u32 hist[16 * 256];              // per-wave radix hist (transposed layout)
    } smT;
    __shared__ __align__(16) float qtile[16 * 68];
    __shared__ float outred[16 * 68];

    const int t = threadIdx.x;
    const int lane = t & 63, w = t >> 6;            // w in [0,16)
    const int quad = lane >> 4, col = lane & 15;
    const int bid = blockIdx.x;
    const int l0 = (bid & 127) * 16;
    const int h  = (bid >> 7) & 15;
    const int b  = bid >> 11;
    const int kvh = h >> 1;

    // ---- load Q tile; zero outred (16*68 = 1088 entries)
    if (t < 256) {
        int q = t >> 4, d4 = (t & 15) * 4;
        *(float4*)&qtile[q * 68 + d4] =
            *(const float4*)(QR + ((size_t)((b * L_ + l0 + q) * NH_ + h)) * DH_ + d4);
    }
    outred[t] = 0.f;
    if (t < 64) outred[1024 + t] = 0.f;
    __syncthreads();

    // ---- build A-frags (hi/lo): A[m=col][k = ks*32 + quad*8 + i]
    union FR { s8v v; unsigned short u[8]; };
    FR ah[2], al[2];
#pragma unroll
    for (int ks = 0; ks < 2; ++ks)
#pragma unroll
        for (int i = 0; i < 8; ++i) {
            float x = qtile[col * 68 + ks * 32 + quad * 8 + i];
            unsigned short hi = bf16rne(x);
            ah[ks].u[i] = hi;
            al[ks].u[i] = bf16rne(x - bf2f(hi));
        }

    // ---- QK^T via MFMA, 6-term hi/lo (score err ~3e-5 abs vs ~4e-3 boundary gaps)
    const size_t slabK = (size_t)(b * KVH_ + kvh) * L_ * DH_;
    const unsigned short* khp = KH + slabK;
    const unsigned short* klp = KL + slabK;
    f4v S[8];
#pragma unroll
    for (int tj = 0; tj < 8; ++tj) {
        int j0 = w * 128 + tj * 16;
        const unsigned short* kh8 = khp + (size_t)(j0 + col) * 64 + quad * 8;
        const unsigned short* kl8 = klp + (size_t)(j0 + col) * 64 + quad * 8;
        s8v bh0 = *(const s8v*)(kh8);
        s8v bh1 = *(const s8v*)(kh8 + 32);
        s8v bl0 = *(const s8v*)(kl8);
        s8v bl1 = *(const s8v*)(kl8 + 32);
        f4v c = {0.f, 0.f, 0.f, 0.f};
        c = MFMA16(ah[0].v, bh0, c);
        c = MFMA16(al[0].v, bh0, c);
        c = MFMA16(ah[0].v, bl0, c);
        c = MFMA16(ah[1].v, bh1, c);
        c = MFMA16(al[1].v, bh1, c);
        c = MFMA16(ah[1].v, bl1, c);
        S[tj] = c * 0.125f;   // DH^-0.5
    }

    // ---- transpose to row ownership: 2 chunks of 1024 cols
    // uk elem i: j = 1024*(i>>4) + 64*(i&15) + lane  (ascending in (i,lane))
    u32 uk[32];
#pragma unroll
    for (int c = 0; c < 2; ++c) {
        if (c) __syncthreads();          // prior chunk reads complete
        if ((w >> 3) == c) {
            int jbase = (w & 7) * 128;
#pragma unroll
            for (int tj = 0; tj < 8; ++tj)
#pragma unroll
                for (int r = 0; r < 4; ++r)
                    smT.Sc[(quad * 4 + r) * 1044 + jbase + tj * 16 + col] = S[tj][r];
        }
        __syncthreads();
#pragma unroll
        for (int i2 = 0; i2 < 16; ++i2)
            uk[c * 16 + i2] = fkey(smT.Sc[w * 1044 + i2 * 64 + lane]);
    }
    __syncthreads();                     // Sc reads done; hist region free

    // ---- wave-local exact top-1024: 4-pass radix, state in registers
    u32 pf = 0u, kq = (u32)TOPK_, ng = 0u;
    u32* hq = &smT.hist[w * 256];
    for (int pass = 0; pass < 4; ++pass) {
        int shift = 24 - 8 * pass;
#pragma unroll
        for (int i = 0; i < 4; ++i) hq[i * 64 + lane] = 0u;
        if (pass == 0) {
            // match-any ballot histogram: all lanes active, digits concentrated
#pragma unroll
            for (int i = 0; i < 32; ++i) {
                u32 d = uk[i] >> 24;
                u64 mm = ~0ull;
#pragma unroll
                for (int bit = 0; bit < 8; ++bit) {
                    u64 bm = __ballot((d >> bit) & 1u);
                    mm &= ((d >> bit) & 1u) ? bm : ~bm;
                }
                if (lane == (int)__builtin_ctzll(mm))
                    atomicAdd(&hq[(d & 3) * 64 + (d >> 2)], (u32)__builtin_popcountll(mm));
            }
        } else {
            u32 pm = 0xFFFFFFFFu << (shift + 8);
#pragma unroll
            for (int i = 0; i < 32; ++i) {
                u32 u = uk[i];
                if ((u & pm) == pf) {
                    u32 d = (u >> shift) & 255u;
                    atomicAdd(&hq[(d & 3) * 64 + (d >> 2)], 1u);
                }
            }
        }
        // reads below may-alias the atomics => real ds ops, wave-ordered
        u32 h0 = hq[0 * 64 + lane], h1 = hq[1 * 64 + lane];
        u32 h2 = hq[2 * 64 + lane], h3 = hq[3 * 64 + lane];
        u32 s4 = h0 + h1 + h2 + h3;
        u32 v = s4;
        for (int off = 1; off < 64; off <<= 1) {
            u32 tmp = __shfl_down(v, off);
            if (lane + off < 64) v += tmp;
        }
        u32 g = v - s4;                  // # keys with digit > 4*lane+3
        u32 hb_[4] = {h0, h1, h2, h3};
        u32 mydig = 0u, myk = 0u, myng = 0u;
        bool found = false;
#pragma unroll
        for (int bb = 3; bb >= 0; --bb) {
            u32 hb = hb_[bb];
            if (hb && g < kq && kq <= g + hb) {   // true for exactly one (lane,bb)
                found = true;
                mydig = (u32)(4 * lane + bb);
                myk   = kq - g;
                myng  = ng + g;
            }
            g += hb;
        }
        u64 fm = __ballot(found);
        int src = (int)__builtin_ctzll(fm);
        pf |= ((u32)__shfl((int)mydig, src)) << shift;
        kq  = (u32)__shfl((int)myk,  src);
        ng  = (u32)__shfl((int)myng, src);
    }

    // ---- selection mask, exact tie handling (wave-local, register state)
    const u32 uth = pf;
    const u32 quota = (u32)TOPK_ - ng;
    u32 selm = 0u, eqm = 0u;
#pragma unroll
    for (int i = 0; i < 32; ++i) {
        u32 u = uk[i];
        if (u > uth) selm |= 1u << i;
        else if (u == uth) eqm |= 1u << i;
    }
    {
        u32 ec = (u32)__builtin_popcount(eqm);
        for (int off = 1; off < 64; off <<= 1) ec += __shfl_xor(ec, off);
        if (ec == quota) {
            selm |= eqm;                 // common case: take all tied entries
        } else {                         // rare: rank ties by lowest index j
            u32 base = 0;
            u64 lmask = ((u64)1 << lane) - 1;
#pragma unroll
            for (int i = 0; i < 32; ++i) {
                u64 mm = __ballot((eqm >> i) & 1u);
                if ((eqm >> i) & 1u) {
                    u32 rk = base + (u32)__builtin_popcountll(mm & lmask);
                    if (rk < quota) selm |= 1u << i;
                }
                base += (u32)__builtin_popcountll(mm);
            }
        }
    }

    // ---- wave-local softmax, invZ folded into P
    float mrow = -3.4e38f;
#pragma unroll
    for (int i = 0; i < 32; ++i) mrow = fmaxf(mrow, fkeyinv(uk[i]));
    for (int off = 1; off < 64; off <<= 1) mrow = fmaxf(mrow, __shfl_xor(mrow, off));
    float z = 0.f;
#pragma unroll
    for (int i = 0; i < 32; ++i) {
        float e = ((selm >> i) & 1u) ? __expf(fkeyinv(uk[i]) - mrow) : 0.f;
        uk[i] = __float_as_uint(e);      // keys dead; reuse as e-storage
        z += e;
    }
    for (int off = 1; off < 64; off <<= 1) z += __shfl_xor(z, off);
    float invZ = 1.0f / z;
    u32 pb[16];                          // packed bf16 P pairs (elem 2i2, 2i2+1)
#pragma unroll
    for (int i2 = 0; i2 < 16; ++i2) {
        u32 lo = (u32)bf16rne(__uint_as_float(uk[2 * i2]) * invZ);
        u32 hi = (u32)bf16rne(__uint_as_float(uk[2 * i2 + 1]) * invZ);
        pb[i2] = lo | (hi << 16);
    }

    // ---- PV: single Pc chunk; wave w covers j in [128w, 128w+128) in 4 sub-chunks
    __syncthreads();                     // hist use done; Pc region free
#pragma unroll
    for (int i = 0; i < 32; ++i) {
        unsigned short pv16 = (unsigned short)(pb[i >> 1] >> ((i & 1) * 16));
        smT.Pc[w * 2072 + 1024 * (i >> 4) + 64 * (i & 15) + lane] = pv16;
    }
    __syncthreads();                     // all P rows written
    const unsigned short* vt = VT + (size_t)(b * KVH_ + kvh) * DH_ * L_;
    f4v acc0 = {0.f, 0.f, 0.f, 0.f}, acc1 = acc0, acc2 = acc0, acc3 = acc0;
#pragma unroll
    for (int kc = 0; kc < 4; ++kc) {
        int jb = w * 128 + kc * 32 + quad * 8;
        s8v ap = *(const s8v*)&smT.Pc[col * 2072 + jb];
        s8v v0 = *(const s8v*)(vt + (size_t)( 0 + col) * L_ + jb);
        s8v v1 = *(const s8v*)(vt + (size_t)(16 + col) * L_ + jb);
        s8v v2 = *(const s8v*)(vt + (size_t)(32 + col) * L_ + jb);
        s8v v3 = *(const s8v*)(vt + (size_t)(48 + col) * L_ + jb);
        acc0 = MFMA16(ap, v0, acc0);
        acc1 = MFMA16(ap, v1, acc1);
        acc2 = MFMA16(ap, v2, acc2);
        acc3 = MFMA16(ap, v3, acc3);
    }

    // ---- cross-wave PV reduction (LDS atomics, padded stride) + store
#pragma unroll
    for (int r = 0; r < 4; ++r) {
        atomicAdd(&outred[(quad * 4 + r) * 68 +  0 + col], acc0[r]);
        atomicAdd(&outred[(quad * 4 + r) * 68 + 16 + col], acc1[r]);
        atomicAdd(&outred[(quad * 4 + r) * 68 + 32 + col], acc2[r]);
        atomicAdd(&outred[(quad * 4 + r) * 68 + 48 + col], acc3[r]);
    }
    __syncthreads();
    if (t < 256) {
        int q = t >> 4, d4 = (t & 15) * 4;
        float4 o = *(float4*)&outred[q * 68 + d4];
        *(float4*)(AO + ((size_t)((b * L_ + l0 + q) * NH_ + h)) * DH_ + d4) = o;
    }
}

// ---------------------------------------------------------------------------
extern "C" void kernel_launch(void* const* d_in, const int* in_sizes, int n_in,
                              void* d_out, int out_size, void* d_ws, size_t ws_size,
                              hipStream_t stream) {
    const float* hs = (const float*)d_in[0];
    const float* wq = (const float*)d_in[1];
    const float* wk = (const float*)d_in[2];
    const float* wv = (const float*)d_in[3];
    const float* wo = (const float*)d_in[4];
    const int*  pos = (const int*)d_in[5];

    float* ws = (float*)d_ws;
    const size_t M1 = 1u << 20;
    float* Qraw = ws;                          // [0, 4M) floats
    float* Kraw = ws + 4 * M1;                 // [4M, 6M) — dead after prep_k
    float* Vraw = ws + 6 * M1;                 // [6M, 8M) — dead after prep_v
    float* AO   = ws + 4 * M1;                 // [4M, 8M) overlays Kraw+Vraw
    unsigned short* WqH = (unsigned short*)(ws +  8 * M1);
    unsigned short* WqL = (unsigned short*)(ws +  8 * M1 + M1 / 2);
    unsigned short* WkH = (unsigned short*)(ws +  9 * M1);
    unsigned short* WkL = (unsigned short*)(ws +  9 * M1 + M1 / 4);
    unsigned short* WvH = (unsigned short*)(ws +  9 * M1 + M1 / 2);
    unsigned short* WvL = (unsigned short*)(ws +  9 * M1 + 3 * (M1 / 4));
    unsigned short* WoH = (unsigned short*)(ws + 10 * M1);
    unsigned short* WoL = (unsigned short*)(ws + 10 * M1 + M1 / 2);
    unsigned short* KH  = (unsigned short*)(ws + 11 * M1);
    unsigned short* KL  = (unsigned short*)(ws + 12 * M1);
    unsigned short* VT  = (unsigned short*)(ws + 13 * M1);
    float* out = (float*)d_out;

    dim3 blk(256);
    prep_wt<<<dim3(16, 16), blk, 0, stream>>>(wq, WqH, WqL, 1024, 1024);
    prep_wt<<<dim3(16,  8), blk, 0, stream>>>(wk, WkH, WkL, 1024, 512);
    prep_wt<<<dim3(16,  8), blk, 0, stream>>>(wv, WvH, WvL, 1024, 512);
    prep_wt<<<dim3(16, 16), blk, 0, stream>>>(wo, WoH, WoL, 1024, 1024);
    gemm_mfma<<<dim3(32, 8), blk, 0, stream>>>(hs, WqH, WqL, Qraw, 1024, 1024);
    gemm_mfma<<<dim3(32, 4), blk, 0, stream>>>(hs, WkH, WkL, Kraw, 1024, 512);
    gemm_mfma<<<dim3(32, 4), blk, 0, stream>>>(hs, WvH, WvL, Vraw, 1024, 512);
    rope_q<<<dim3(8192), blk, 0, stream>>>(Qraw, pos);
    prep_k<<<dim3(8192), blk, 0, stream>>>(Kraw, KH, KL, pos);
    prep_v<<<dim3(512),  blk, 0, stream>>>(Vraw, VT);
    attn<<<dim3(4096), dim3(1024), 0, stream>>>(Qraw, KH, KL, VT, AO);
    gemm_mfma<<<dim3(32, 8), blk, 0, stream>>>(AO, WoH, WoL, out, 1024, 1024);
}

// Round 8
// 1295.912 us; speedup vs baseline: 3.7318x; 3.7318x over previous
//
#include <hip/hip_runtime.h>
#include <cstdint>
#include <cstddef>

typedef unsigned int u32;
typedef unsigned long long u64;
typedef __attribute__((ext_vector_type(8))) short s8v;   // 8 bf16 (4 VGPRs)
typedef __attribute__((ext_vector_type(4))) float f4v;   // MFMA C/D

#define B_   2
#define L_   2048
#define D_   1024
#define NH_  16
#define KVH_ 8
#define DH_  64
#define TOPK_ 1024

#define MFMA16(a, b, c) __builtin_amdgcn_mfma_f32_16x16x32_bf16(a, b, c, 0, 0, 0)

// order-preserving float->uint key (descending float == descending uint)
__device__ __forceinline__ u32 fkey(float s) {
    u32 b = __float_as_uint(s);
    return b ^ ((u32)((int)b >> 31) | 0x80000000u);
}
// exact inverse of fkey
__device__ __forceinline__ float fkeyinv(u32 k) {
    u32 b = (k & 0x80000000u) ? (k ^ 0x80000000u) : ~k;
    return __uint_as_float(b);
}
// fp32 -> bf16 round-to-nearest-even, as raw ushort
__device__ __forceinline__ unsigned short bf16rne(float x) {
    u32 u = __float_as_uint(x);
    u32 r = (u + 0x7FFFu + ((u >> 16) & 1u)) >> 16;
    return (unsigned short)r;
}
__device__ __forceinline__ float bf2f(unsigned short h) {
    return __uint_as_float((u32)h << 16);
}

// ---------------------------------------------------------------------------
// W [K][N] fp32 -> WtH/WtL [N][K] bf16 hi/lo (transpose + split). grid (K/64, N/64)
// ---------------------------------------------------------------------------
__global__ __launch_bounds__(256) void prep_wt(const float* __restrict__ W,
                                               unsigned short* __restrict__ WtH,
                                               unsigned short* __restrict__ WtL,
                                               int K, int N) {
    __shared__ float tile[64 * 65];
    int k0 = blockIdx.x * 64, n0 = blockIdx.y * 64;
    int t = threadIdx.x;
#pragma unroll
    for (int i = 0; i < 16; ++i) {
        int idx = t + i * 256;
        int kk = idx >> 6, nn = idx & 63;
        tile[kk * 65 + nn] = W[(size_t)(k0 + kk) * N + n0 + nn];
    }
    __syncthreads();
#pragma unroll
    for (int i = 0; i < 16; ++i) {
        int idx = t + i * 256;
        int nn = idx >> 6, kk = idx & 63;
        float x = tile[kk * 65 + nn];
        unsigned short hi = bf16rne(x);
        unsigned short lo = bf16rne(x - bf2f(hi));
        WtH[(size_t)(n0 + nn) * K + k0 + kk] = hi;
        WtL[(size_t)(n0 + nn) * K + k0 + kk] = lo;
    }
}

// ---------------------------------------------------------------------------
// MFMA GEMM: C[M][N] fp32 = A[M][K] fp32 @ Wt([N][K] bf16 hi/lo), 3-term hi/lo.
// BM=128, BN=128, BK=32; 256 threads (4 waves, 2x2 of 64x64). grid (M/128, N/128)
// ---------------------------------------------------------------------------
__global__ __launch_bounds__(256) void gemm_mfma(
    const float* __restrict__ A,
    const unsigned short* __restrict__ Wh,
    const unsigned short* __restrict__ Wl,
    float* __restrict__ C, int K, int N) {
    __shared__ __align__(16) unsigned short lAh[128 * 40];
    __shared__ __align__(16) unsigned short lAl[128 * 40];
    __shared__ __align__(16) unsigned short lBh[128 * 40];
    __shared__ __align__(16) unsigned short lBl[128 * 40];
    const int t = threadIdx.x, lane = t & 63, w = t >> 6;
    const int quad = lane >> 4, col = lane & 15;
    const int wm = w >> 1, wn = w & 1;
    const int m0 = blockIdx.x * 128, n0 = blockIdx.y * 128;
    const int sr = t >> 1, sk = (t & 1) * 16;

    f4v acc[4][4];
#pragma unroll
    for (int i = 0; i < 4; ++i)
#pragma unroll
        for (int j = 0; j < 4; ++j) acc[i][j] = (f4v){0.f, 0.f, 0.f, 0.f};

    for (int k0 = 0; k0 < K; k0 += 32) {
        const float* ap = A + (size_t)(m0 + sr) * K + k0 + sk;
        float4 a0 = *(const float4*)(ap);
        float4 a1 = *(const float4*)(ap + 4);
        float4 a2 = *(const float4*)(ap + 8);
        float4 a3 = *(const float4*)(ap + 12);
        s8v bh0 = *(const s8v*)(Wh + (size_t)(n0 + sr) * K + k0 + sk);
        s8v bh1 = *(const s8v*)(Wh + (size_t)(n0 + sr) * K + k0 + sk + 8);
        s8v bl0 = *(const s8v*)(Wl + (size_t)(n0 + sr) * K + k0 + sk);
        s8v bl1 = *(const s8v*)(Wl + (size_t)(n0 + sr) * K + k0 + sk + 8);
        float av[16] = {a0.x, a0.y, a0.z, a0.w, a1.x, a1.y, a1.z, a1.w,
                        a2.x, a2.y, a2.z, a2.w, a3.x, a3.y, a3.z, a3.w};
        union { s8v v; unsigned short u[8]; } ah_[2], al_[2];
#pragma unroll
        for (int i = 0; i < 16; ++i) {
            unsigned short hi = bf16rne(av[i]);
            ah_[i >> 3].u[i & 7] = hi;
            al_[i >> 3].u[i & 7] = bf16rne(av[i] - bf2f(hi));
        }
        __syncthreads();
        *(s8v*)&lAh[sr * 40 + sk]     = ah_[0].v;
        *(s8v*)&lAh[sr * 40 + sk + 8] = ah_[1].v;
        *(s8v*)&lAl[sr * 40 + sk]     = al_[0].v;
        *(s8v*)&lAl[sr * 40 + sk + 8] = al_[1].v;
        *(s8v*)&lBh[sr * 40 + sk]     = bh0;
        *(s8v*)&lBh[sr * 40 + sk + 8] = bh1;
        *(s8v*)&lBl[sr * 40 + sk]     = bl0;
        *(s8v*)&lBl[sr * 40 + sk + 8] = bl1;
        __syncthreads();
        s8v amh[4], aml[4], bnh[4], bnl[4];
#pragma unroll
        for (int mt = 0; mt < 4; ++mt) {
            amh[mt] = *(s8v*)&lAh[(wm * 64 + mt * 16 + col) * 40 + quad * 8];
            aml[mt] = *(s8v*)&lAl[(wm * 64 + mt * 16 + col) * 40 + quad * 8];
        }
#pragma unroll
        for (int nt = 0; nt < 4; ++nt) {
            bnh[nt] = *(s8v*)&lBh[(wn * 64 + nt * 16 + col) * 40 + quad * 8];
            bnl[nt] = *(s8v*)&lBl[(wn * 64 + nt * 16 + col) * 40 + quad * 8];
        }
#pragma unroll
        for (int mt = 0; mt < 4; ++mt)
#pragma unroll
            for (int nt = 0; nt < 4; ++nt) {
                acc[mt][nt] = MFMA16(amh[mt], bnh[nt], acc[mt][nt]);
                acc[mt][nt] = MFMA16(amh[mt], bnl[nt], acc[mt][nt]);
                acc[mt][nt] = MFMA16(aml[mt], bnh[nt], acc[mt][nt]);
            }
    }
#pragma unroll
    for (int mt = 0; mt < 4; ++mt)
#pragma unroll
        for (int nt = 0; nt < 4; ++nt)
#pragma unroll
            for (int r = 0; r < 4; ++r)
                C[(size_t)(m0 + wm * 64 + mt * 16 + quad * 4 + r) * N +
                  n0 + wn * 64 + nt * 16 + col] = acc[mt][nt][r];
}

// ---------------------------------------------------------------------------
// RoPE on Q, in place. Layout [b][l][h][d].
// ---------------------------------------------------------------------------
__global__ __launch_bounds__(256) void rope_q(float* __restrict__ Q,
                                              const int* __restrict__ pos) {
    int tid = blockIdx.x * 256 + threadIdx.x;
    int dl = tid & 31;
    int h  = (tid >> 5) & 15;
    int l  = (tid >> 9) & 2047;
    int b  = tid >> 20;
    size_t base = ((size_t)(b * L_ + l) * NH_ + h) * DH_;
    float x1 = Q[base + dl];
    float x2 = Q[base + dl + 32];
    float p = (float)pos[b * L_ + l];
    float invf = (float)pow(10000.0, -(double)dl / 32.0);
    float a = p * invf;
    float s, c;
    sincosf(a, &s, &c);
    Q[base + dl]      = x1 * c - x2 * s;
    Q[base + dl + 32] = x2 * c + x1 * s;
}

// ---------------------------------------------------------------------------
// RoPE on K + hi/lo bf16 split, layout [b][kvh][l][d]
// ---------------------------------------------------------------------------
__global__ __launch_bounds__(256) void prep_k(const float* __restrict__ Kraw,
                                              unsigned short* __restrict__ KHp,
                                              unsigned short* __restrict__ KLp,
                                              const int* __restrict__ pos) {
    int tid = blockIdx.x * 256 + threadIdx.x;
    int d   = tid & 63;
    int l   = (tid >> 6) & 2047;
    int kvh = (tid >> 17) & 7;
    int b   = tid >> 20;
    size_t src = ((size_t)(b * L_ + l) * KVH_ + kvh) * DH_;
    float x  = Kraw[src + d];
    int dp   = (d < 32) ? d + 32 : d - 32;
    float xp = Kraw[src + dp];
    float p = (float)pos[b * L_ + l];
    int i = d & 31;
    float invf = (float)pow(10000.0, -(double)i / 32.0);
    float a = p * invf;
    float s, c;
    sincosf(a, &s, &c);
    float out = (d < 32) ? (x * c - xp * s) : (x * c + xp * s);
    unsigned short hi = bf16rne(out);
    unsigned short lo = bf16rne(out - bf2f(hi));
    size_t dst = ((size_t)(b * KVH_ + kvh) * L_ + l) * DH_ + d;
    KHp[dst] = hi;
    KLp[dst] = lo;
}

// ---------------------------------------------------------------------------
// V transpose to bf16: Vraw[b][l][kvh][d] -> VT[b][kvh][d][l]
// ---------------------------------------------------------------------------
__global__ __launch_bounds__(256) void prep_v(const float* __restrict__ Vraw,
                                              unsigned short* __restrict__ VTp) {
    __shared__ float tile[64 * 65];
    int bid = blockIdx.x;
    int lb  = bid & 31;
    int kvh = (bid >> 5) & 7;
    int b   = bid >> 8;
    int l0  = lb * 64;
    int t   = threadIdx.x;
#pragma unroll
    for (int i = 0; i < 16; ++i) {
        int idx = t + i * 256;
        int ll = idx >> 6, d = idx & 63;
        tile[ll * 65 + d] = Vraw[((size_t)(b * L_ + l0 + ll) * KVH_ + kvh) * DH_ + d];
    }
    __syncthreads();
#pragma unroll
    for (int i = 0; i < 16; ++i) {
        int idx = t + i * 256;
        int d = idx >> 6, ll = idx & 63;
        VTp[((size_t)(b * KVH_ + kvh) * DH_ + d) * L_ + l0 + ll] = bf16rne(tile[ll * 65 + d]);
    }
}

// ---------------------------------------------------------------------------
// Fused sparse attention, R8: 8 q-rows/block, 512 threads (8 waves), grid 8192.
// Rationale: 1024-thread blocks run 1 block/CU on this HW (R4/R6 occupancy 48%,
// every barrier drains the CU). 512-thread blocks at ~38 KB LDS and <=64 VGPR
// (R6-proven shapes: short live ranges, plain atomics) allow 3-4 blocks/CU.
// QK in 2 J-passes of 1024 cols (S[8] dies per pass); wave w owns row w for
// selection/softmax (wave-local, register state); PV per-wave 256-col range
// with col&7 A-row aliasing (M-half-empty MFMAs; MFMA pipe is ~3% busy).
// ---------------------------------------------------------------------------
__global__ __launch_bounds__(512) void attn(
    const float* __restrict__ QR,
    const unsigned short* __restrict__ KH,
    const unsigned short* __restrict__ KL,
    const unsigned short* __restrict__ VT,
    float* __restrict__ AO) {

    __shared__ __align__(16) union {
        float Sc[8 * 1044];              // J-pass transpose chunk (33.4 KB)
        unsigned short Pc[8 * 2072];     // P rows bf16 (33.2 KB)
        u32 hist[8 * 256];               // per-wave radix hist (8 KB)
    } smT;
    __shared__ __align__(16) float qtile[8 * 68];
    __shared__ float outred[8 * 68];

    const int t = threadIdx.x;
    const int lane = t & 63, w = t >> 6;            // w in [0,8)
    const int quad = lane >> 4, col = lane & 15;
    const int bid = blockIdx.x;
    const int l0 = (bid & 255) * 8;
    const int h  = (bid >> 8) & 15;
    const int b  = bid >> 12;
    const int kvh = h >> 1;

    // ---- load Q tile (8 rows); zero outred
    if (t < 128) {
        int q = t >> 4, d4 = (t & 15) * 4;
        *(float4*)&qtile[q * 68 + d4] =
            *(const float4*)(QR + ((size_t)((b * L_ + l0 + q) * NH_ + h)) * DH_ + d4);
    }
    if (t < 272) { outred[t] = 0.f; outred[t + 272] = 0.f; }
    __syncthreads();

    // ---- build A-frags (hi/lo): A[m=col][k = ks*32 + quad*8 + i]; col>=8 dups row col&7
    union FR { s8v v; unsigned short u[8]; };
    FR ah[2], al[2];
#pragma unroll
    for (int ks = 0; ks < 2; ++ks)
#pragma unroll
        for (int i = 0; i < 8; ++i) {
            float x = qtile[(col & 7) * 68 + ks * 32 + quad * 8 + i];
            unsigned short hi = bf16rne(x);
            ah[ks].u[i] = hi;
            al[ks].u[i] = bf16rne(x - bf2f(hi));
        }

    // ---- QK^T + transpose, 2 J-passes of 1024 cols each
    const size_t slabK = (size_t)(b * KVH_ + kvh) * L_ * DH_;
    const unsigned short* khp = KH + slabK;
    const unsigned short* klp = KL + slabK;
    u32 uk[32];   // row-w keys; elem i: j = 1024*(i>>4) + 64*(i&15) + lane
#pragma unroll
    for (int jp = 0; jp < 2; ++jp) {
        f4v S[8];
#pragma unroll
        for (int tj = 0; tj < 8; ++tj) {
            int j0 = jp * 1024 + w * 128 + tj * 16;
            const unsigned short* kh8 = khp + (size_t)(j0 + col) * 64 + quad * 8;
            const unsigned short* kl8 = klp + (size_t)(j0 + col) * 64 + quad * 8;
            s8v bh0 = *(const s8v*)(kh8);
            s8v bh1 = *(const s8v*)(kh8 + 32);
            s8v bl0 = *(const s8v*)(kl8);
            s8v bl1 = *(const s8v*)(kl8 + 32);
            f4v c = {0.f, 0.f, 0.f, 0.f};
            c = MFMA16(ah[0].v, bh0, c);
            c = MFMA16(al[0].v, bh0, c);
            c = MFMA16(ah[0].v, bl0, c);
            c = MFMA16(ah[1].v, bh1, c);
            c = MFMA16(al[1].v, bh1, c);
            c = MFMA16(ah[1].v, bl1, c);
            S[tj] = c * 0.125f;   // DH^-0.5
        }
        if (jp) __syncthreads();         // Sc reads of jp0 complete everywhere
        // write: rows q = quad*4+r < 8 -> quads 0,1 only
        if (quad < 2) {
#pragma unroll
            for (int tj = 0; tj < 8; ++tj)
#pragma unroll
                for (int r = 0; r < 4; ++r)
                    smT.Sc[(quad * 4 + r) * 1044 + w * 128 + tj * 16 + col] = S[tj][r];
        }
        __syncthreads();
#pragma unroll
        for (int i2 = 0; i2 < 16; ++i2)
            uk[jp * 16 + i2] = fkey(smT.Sc[w * 1044 + i2 * 64 + lane]);
    }
    __syncthreads();                     // Sc reads done; hist region free

    // ---- wave-local exact top-1024: 4-pass radix, state in registers
    u32 pf = 0u, kq = (u32)TOPK_, ng = 0u;
    u32* hq = &smT.hist[w * 256];
    for (int pass = 0; pass < 4; ++pass) {
        int shift = 24 - 8 * pass;
#pragma unroll
        for (int i = 0; i < 4; ++i) hq[i * 64 + lane] = 0u;
        u32 pm = pass ? (0xFFFFFFFFu << (shift + 8)) : 0u;
#pragma unroll
        for (int i = 0; i < 32; ++i) {
            u32 u = uk[i];
            if ((u & pm) == pf) {
                u32 d = (u >> shift) & 255u;
                atomicAdd(&hq[(d & 3) * 64 + (d >> 2)], 1u);
            }
        }
        // reads may-alias the atomics => real ds ops, wave-ordered
        u32 h0 = hq[0 * 64 + lane], h1 = hq[1 * 64 + lane];
        u32 h2 = hq[2 * 64 + lane], h3 = hq[3 * 64 + lane];
        u32 s4 = h0 + h1 + h2 + h3;
        u32 v = s4;
        for (int off = 1; off < 64; off <<= 1) {
            u32 tmp = __shfl_down(v, off);
            if (lane + off < 64) v += tmp;
        }
        u32 g = v - s4;                  // # keys with digit > 4*lane+3
        u32 hb_[4] = {h0, h1, h2, h3};
        u32 mydig = 0u, myk = 0u, myng = 0u;
        bool found = false;
#pragma unroll
        for (int bb = 3; bb >= 0; --bb) {
            u32 hb = hb_[bb];
            if (hb && g < kq && kq <= g + hb) {   // true for exactly one (lane,bb)
                found = true;
                mydig = (u32)(4 * lane + bb);
                myk   = kq - g;
                myng  = ng + g;
            }
            g += hb;
        }
        u64 fm = __ballot(found);
        int src = (int)__builtin_ctzll(fm);
        pf |= ((u32)__shfl((int)mydig, src)) << shift;
        kq  = (u32)__shfl((int)myk,  src);
        ng  = (u32)__shfl((int)myng, src);
    }

    // ---- selection mask, exact tie handling (wave-local, register state)
    const u32 uth = pf;
    const u32 quota = (u32)TOPK_ - ng;
    u32 selm = 0u, eqm = 0u;
#pragma unroll
    for (int i = 0; i < 32; ++i) {
        u32 u = uk[i];
        if (u > uth) selm |= 1u << i;
        else if (u == uth) eqm |= 1u << i;
    }
    {
        u32 ec = (u32)__builtin_popcount(eqm);
        for (int off = 1; off < 64; off <<= 1) ec += __shfl_xor(ec, off);
        if (ec == quota) {
            selm |= eqm;                 // common case: take all tied entries
        } else {                         // rare: rank ties by lowest index j
            u32 base = 0;
            u64 lmask = ((u64)1 << lane) - 1;
#pragma unroll
            for (int i = 0; i < 32; ++i) {
                u64 mm = __ballot((eqm >> i) & 1u);
                if ((eqm >> i) & 1u) {
                    u32 rk = base + (u32)__builtin_popcountll(mm & lmask);
                    if (rk < quota) selm |= 1u << i;
                }
                base += (u32)__builtin_popcountll(mm);
            }
        }
    }

    // ---- wave-local softmax, invZ folded into P
    float mrow = -3.4e38f;
#pragma unroll
    for (int i = 0; i < 32; ++i) mrow = fmaxf(mrow, fkeyinv(uk[i]));
    for (int off = 1; off < 64; off <<= 1) mrow = fmaxf(mrow, __shfl_xor(mrow, off));
    float z = 0.f;
#pragma unroll
    for (int i = 0; i < 32; ++i) {
        float e = ((selm >> i) & 1u) ? __expf(fkeyinv(uk[i]) - mrow) : 0.f;
        uk[i] = __float_as_uint(e);      // keys dead; reuse as e-storage
        z += e;
    }
    for (int off = 1; off < 64; off <<= 1) z += __shfl_xor(z, off);
    float invZ = 1.0f / z;

    // ---- P -> Pc (bf16, invZ folded); row w, 2 sub-writes per reg pair
    __syncthreads();                     // hist use done; Pc region free
#pragma unroll
    for (int i = 0; i < 32; ++i) {
        unsigned short pv16 = bf16rne(__uint_as_float(uk[i]) * invZ);
        smT.Pc[w * 2072 + 1024 * (i >> 4) + 64 * (i & 15) + lane] = pv16;
    }
    __syncthreads();                     // all P rows written

    // ---- PV via MFMA; wave w covers j in [256w, 256w+256) in 8 sub-chunks of 32
    const unsigned short* vt = VT + (size_t)(b * KVH_ + kvh) * DH_ * L_;
    f4v acc0 = {0.f, 0.f, 0.f, 0.f}, acc1 = acc0, acc2 = acc0, acc3 = acc0;
#pragma unroll
    for (int kc = 0; kc < 8; ++kc) {
        int jb = w * 256 + kc * 32 + quad * 8;
        s8v ap = *(const s8v*)&smT.Pc[(col & 7) * 2072 + jb];
        s8v v0 = *(const s8v*)(vt + (size_t)( 0 + col) * L_ + jb);
        s8v v1 = *(const s8v*)(vt + (size_t)(16 + col) * L_ + jb);
        s8v v2 = *(const s8v*)(vt + (size_t)(32 + col) * L_ + jb);
        s8v v3 = *(const s8v*)(vt + (size_t)(48 + col) * L_ + jb);
        acc0 = MFMA16(ap, v0, acc0);
        acc1 = MFMA16(ap, v1, acc1);
        acc2 = MFMA16(ap, v2, acc2);
        acc3 = MFMA16(ap, v3, acc3);
    }

    // ---- cross-wave PV reduction (rows 0-7 live in quads 0,1) + store
    if (quad < 2) {
#pragma unroll
        for (int r = 0; r < 4; ++r) {
            atomicAdd(&outred[(quad * 4 + r) * 68 +  0 + col], acc0[r]);
            atomicAdd(&outred[(quad * 4 + r) * 68 + 16 + col], acc1[r]);
            atomicAdd(&outred[(quad * 4 + r) * 68 + 32 + col], acc2[r]);
            atomicAdd(&outred[(quad * 4 + r) * 68 + 48 + col], acc3[r]);
        }
    }
    __syncthreads();
    if (t < 128) {
        int q = t >> 4, d4 = (t & 15) * 4;
        float4 o = *(float4*)&outred[q * 68 + d4];
        *(float4*)(AO + ((size_t)((b * L_ + l0 + q) * NH_ + h)) * DH_ + d4) = o;
    }
}

// ---------------------------------------------------------------------------
extern "C" void kernel_launch(void* const* d_in, const int* in_sizes, int n_in,
                              void* d_out, int out_size, void* d_ws, size_t ws_size,
                              hipStream_t stream) {
    const float* hs = (const float*)d_in[0];
    const float* wq = (const float*)d_in[1];
    const float* wk = (const float*)d_in[2];
    const float* wv = (const float*)d_in[3];
    const float* wo = (const float*)d_in[4];
    const int*  pos = (const int*)d_in[5];

    float* ws = (float*)d_ws;
    const size_t M1 = 1u << 20;
    float* Qraw = ws;                          // [0, 4M) floats
    float* Kraw = ws + 4 * M1;                 // [4M, 6M) — dead after prep_k
    float* Vraw = ws + 6 * M1;                 // [6M, 8M) — dead after prep_v
    float* AO   = ws + 4 * M1;                 // [4M, 8M) overlays Kraw+Vraw
    unsigned short* WqH = (unsigned short*)(ws +  8 * M1);
    unsigned short* WqL = (unsigned short*)(ws +  8 * M1 + M1 / 2);
    unsigned short* WkH = (unsigned short*)(ws +  9 * M1);
    unsigned short* WkL = (unsigned short*)(ws +  9 * M1 + M1 / 4);
    unsigned short* WvH = (unsigned short*)(ws +  9 * M1 + M1 / 2);
    unsigned short* WvL = (unsigned short*)(ws +  9 * M1 + 3 * (M1 / 4));
    unsigned short* WoH = (unsigned short*)(ws + 10 * M1);
    unsigned short* WoL = (unsigned short*)(ws + 10 * M1 + M1 / 2);
    unsigned short* KH  = (unsigned short*)(ws + 11 * M1);
    unsigned short* KL  = (unsigned short*)(ws + 12 * M1);
    unsigned short* VT  = (unsigned short*)(ws + 13 * M1);
    float* out = (float*)d_out;

    dim3 blk(256);
    prep_wt<<<dim3(16, 16), blk, 0, stream>>>(wq, WqH, WqL, 1024, 1024);
    prep_wt<<<dim3(16,  8), blk, 0, stream>>>(wk, WkH, WkL, 1024, 512);
    prep_wt<<<dim3(16,  8), blk, 0, stream>>>(wv, WvH, WvL, 1024, 512);
    prep_wt<<<dim3(16, 16), blk, 0, stream>>>(wo, WoH, WoL, 1024, 1024);
    gemm_mfma<<<dim3(32, 8), blk, 0, stream>>>(hs, WqH, WqL, Qraw, 1024, 1024);
    gemm_mfma<<<dim3(32, 4), blk, 0, stream>>>(hs, WkH, WkL, Kraw, 1024, 512);
    gemm_mfma<<<dim3(32, 4), blk, 0, stream>>>(hs, WvH, WvL, Vraw, 1024, 512);
    rope_q<<<dim3(8192), blk, 0, stream>>>(Qraw, pos);
    prep_k<<<dim3(8192), blk, 0, stream>>>(Kraw, KH, KL, pos);
    prep_v<<<dim3(512),  blk, 0, stream>>>(Vraw, VT);
    attn<<<dim3(8192), dim3(512), 0, stream>>>(Qraw, KH, KL, VT, AO);
    gemm_mfma<<<dim3(32, 8), blk, 0, stream>>>(AO, WoH, WoL, out, 1024, 1024);
}